// Round 2
// baseline (145.008 us; speedup 1.0000x reference)
//
#include <hip/hip_runtime.h>
#include <math.h>

#define HW 512
#define NB 16
#define TLX 128          // tile width in pixels
#define TLY 8            // tile height in pixels
#define LDSW 136         // TLX + 8 (4-col halo each side, keeps float4 alignment)
#define LDSH 14          // TLY + 6
#define N_PIX (NB * HW * HW)  // 4194304

// Phase 1: per 128x8 tile, compute avg = exp(-boxmean), dif = sum w*relu(patch-center),
// write both, accumulate sum(suppression^2) via one atomic per block.
__global__ __launch_bounds__(256) void li_phase1(
    const float* __restrict__ x, const float* __restrict__ kw,
    float* __restrict__ out_avg, float* __restrict__ out_dif,
    float* __restrict__ ss_accum)
{
    __shared__ float tile[LDSH * LDSW];   // 7616 B
    __shared__ float wsum[4];

    const int tid = threadIdx.x;
    const int bx = blockIdx.x, by = blockIdx.y, b = blockIdx.z;
    const int x0 = bx * TLX, y0 = by * TLY;
    const float* xb = x + (size_t)b * (HW * HW);

    // Stage 14 x 136 tile with zero halo (global cols x0-4 .. x0+131, rows y0-3 .. y0+10)
    for (int idx = tid; idx < LDSH * LDSW; idx += 256) {
        int r = idx / LDSW;
        int c = idx - r * LDSW;
        int gy = y0 - 3 + r;
        int gx = x0 - 4 + c;
        float v = 0.f;
        if ((unsigned)gy < HW && (unsigned)gx < HW) v = xb[gy * HW + gx];
        tile[idx] = v;
    }
    __syncthreads();

    const int rt = tid >> 5;        // 0..7  : row within tile
    const int tp = tid & 31;        // 0..31 : 4-pixel group within row

    // Load this thread's 7x12 window (only cols 1..10 are live) into registers
    // via aligned ds_read_b128: base col = 4*tp (16B aligned since LDSW%4==0).
    float win[7][12];
#pragma unroll
    for (int r = 0; r < 7; r++) {
        const float* rp = &tile[(rt + r) * LDSW + 4 * tp];
        float4 a = *(const float4*)(rp);
        float4 bb = *(const float4*)(rp + 4);
        float4 c = *(const float4*)(rp + 8);
        win[r][0] = a.x;  win[r][1] = a.y;  win[r][2] = a.z;  win[r][3] = a.w;
        win[r][4] = bb.x; win[r][5] = bb.y; win[r][6] = bb.z; win[r][7] = bb.w;
        win[r][8] = c.x;  win[r][9] = c.y;  win[r][10] = c.z; win[r][11] = c.w;
    }

    // Box sums (sliding horizontally), 4 pixels p=0..3, center window col = p+4
    float bsum0 = 0.f, bsum1 = 0.f, bsum2 = 0.f, bsum3 = 0.f;
#pragma unroll
    for (int r = 0; r < 7; r++) {
        float rs0 = ((win[r][1] + win[r][2]) + (win[r][3] + win[r][4])) +
                    ((win[r][5] + win[r][6]) + win[r][7]);
        float rs1 = rs0 - win[r][1] + win[r][8];
        float rs2 = rs1 - win[r][2] + win[r][9];
        float rs3 = rs2 - win[r][3] + win[r][10];
        bsum0 += rs0; bsum1 += rs1; bsum2 += rs2; bsum3 += rs3;
    }

    float cen[4] = { win[3][4], win[3][5], win[3][6], win[3][7] };
    float dif[4] = { 0.f, 0.f, 0.f, 0.f };
#pragma unroll
    for (int r = 0; r < 7; r++) {
#pragma unroll
        for (int dj = 0; dj < 7; dj++) {
            const float w = kw[r * 7 + dj];   // uniform -> s_load, SGPR operand
#pragma unroll
            for (int p = 0; p < 4; p++)
                dif[p] = fmaf(w, fmaxf(win[r][p + 1 + dj] - cen[p], 0.f), dif[p]);
        }
    }

    const int gy = y0 + rt;
    const size_t gi = (size_t)b * (HW * HW) + (size_t)gy * HW + x0 + 4 * tp;
    float4 av, dv;
    av.x = __expf(-bsum0 * (1.0f / 49.0f));
    av.y = __expf(-bsum1 * (1.0f / 49.0f));
    av.z = __expf(-bsum2 * (1.0f / 49.0f));
    av.w = __expf(-bsum3 * (1.0f / 49.0f));
    dv.x = dif[0]; dv.y = dif[1]; dv.z = dif[2]; dv.w = dif[3];
    *(float4*)(out_avg + gi) = av;
    *(float4*)(out_dif + gi) = dv;

    float s0 = 0.1f * av.x + 0.9f * dv.x;
    float s1 = 0.1f * av.y + 0.9f * dv.y;
    float s2 = 0.1f * av.z + 0.9f * dv.z;
    float s3 = 0.1f * av.w + 0.9f * dv.w;
    float ss = (s0 * s0 + s1 * s1) + (s2 * s2 + s3 * s3);

#pragma unroll
    for (int off = 32; off > 0; off >>= 1)
        ss += __shfl_down(ss, off, 64);
    if ((tid & 63) == 0) wsum[tid >> 6] = ss;
    __syncthreads();
    if (tid == 0)
        atomicAdd(ss_accum, (wsum[0] + wsum[1]) + (wsum[2] + wsum[3]));
}

// Phase 2: identical grid/tile mapping as phase 1 so each block (same linear id
// -> same XCD heuristically) re-reads data it just wrote: local-L2 hits.
__global__ __launch_bounds__(256) void li_phase2(
    const float* __restrict__ x, const float* __restrict__ avg,
    const float* __restrict__ dif, const float* __restrict__ ss,
    float* __restrict__ mask)
{
    const int tid = threadIdx.x;
    const int bx = blockIdx.x, by = blockIdx.y, b = blockIdx.z;
    const int gy = by * TLY + (tid >> 5);
    const size_t gi = (size_t)b * (HW * HW) + (size_t)gy * HW + bx * TLX + 4 * (tid & 31);

    const float inv = 1.0f / sqrtf(*ss);
    float4 xv = *(const float4*)(x + gi);
    float4 av = *(const float4*)(avg + gi);
    float4 dv = *(const float4*)(dif + gi);
    float4 m;
    m.x = (xv.x > (0.1f * av.x + 0.9f * dv.x) * inv) ? 1.f : 0.f;
    m.y = (xv.y > (0.1f * av.y + 0.9f * dv.y) * inv) ? 1.f : 0.f;
    m.z = (xv.z > (0.1f * av.z + 0.9f * dv.z) * inv) ? 1.f : 0.f;
    m.w = (xv.w > (0.1f * av.w + 0.9f * dv.w) * inv) ? 1.f : 0.f;
    *(float4*)(mask + gi) = m;
}

extern "C" void kernel_launch(void* const* d_in, const int* in_sizes, int n_in,
                              void* d_out, int out_size, void* d_ws, size_t ws_size,
                              hipStream_t stream) {
    const float* x  = (const float*)d_in[0];
    const float* kw = (const float*)d_in[1];
    float* out  = (float*)d_out;
    float* mask = out;
    float* avg  = out + N_PIX;
    float* dif  = out + 2 * (size_t)N_PIX;
    float* ss   = (float*)d_ws;

    hipMemsetAsync(d_ws, 0, sizeof(float), stream);

    dim3 g(HW / TLX, HW / TLY, NB);   // 4 x 64 x 16 = 4096 blocks
    li_phase1<<<g, 256, 0, stream>>>(x, kw, avg, dif, ss);
    li_phase2<<<g, 256, 0, stream>>>(x, avg, dif, ss, mask);
}

// Round 3
// 137.104 us; speedup vs baseline: 1.0577x; 1.0577x over previous
//
#include <hip/hip_runtime.h>
#include <math.h>

#define HW 512
#define NB 16
#define TLX 128          // tile width in pixels
#define TLY 8            // tile height in pixels
#define LDSW 136         // TLX + 8 (4-col halo each side, float4-aligned rows)
#define LDSH 14          // TLY + 6
#define N_PIX (NB * HW * HW)  // 4194304

// Phase 1: per 128x8 tile compute avg = exp(-boxmean), dif = sum w*relu(patch-center),
// ratio = x / (0.1*avg + 0.9*dif). Write avg, dif, ratio; atomicAdd sum(s^2).
__global__ __launch_bounds__(256) void li_phase1(
    const float* __restrict__ x, const float* __restrict__ kw,
    float* __restrict__ out_ratio, float* __restrict__ out_avg,
    float* __restrict__ out_dif, float* __restrict__ ss_accum)
{
    __shared__ float tile[LDSH * LDSW];   // 7616 B
    __shared__ float wsum[4];

    const int tid = threadIdx.x;
    const int bx = blockIdx.x, by = blockIdx.y, b = blockIdx.z;
    const int x0 = bx * TLX, y0 = by * TLY;
    const float* xb = x + (size_t)b * (HW * HW);

    // Stage 14 x 136 tile with zero halo, float4 granularity (all-or-nothing per
    // quad since x0 % 4 == 0 and HW % 4 == 0).
    for (int idx = tid; idx < LDSH * (LDSW / 4); idx += 256) {
        int r = idx / (LDSW / 4);
        int c4 = idx - r * (LDSW / 4);
        int gy = y0 - 3 + r;
        int gx = x0 - 4 + c4 * 4;
        float4 v = make_float4(0.f, 0.f, 0.f, 0.f);
        if ((unsigned)gy < HW && (unsigned)gx < HW)
            v = *(const float4*)(xb + gy * HW + gx);
        *(float4*)&tile[r * LDSW + c4 * 4] = v;
    }
    __syncthreads();

    const int rt = tid >> 5;        // 0..7  : row within tile
    const int tp = tid & 31;        // 0..31 : 4-pixel group within row
    const int c0 = 4 * tp;          // window col 0 in LDS coords

    // Centers: middle float4 of window row 3
    float4 cf = *(const float4*)&tile[(rt + 3) * LDSW + c0 + 4];
    const float cen[4] = { cf.x, cf.y, cf.z, cf.w };

    float bsum[4] = { 0.f, 0.f, 0.f, 0.f };
    float dif[4]  = { 0.f, 0.f, 0.f, 0.f };

#pragma unroll
    for (int r = 0; r < 7; r++) {
        const float* rp = &tile[(rt + r) * LDSW + c0];
        float4 a = *(const float4*)(rp);
        float4 bb = *(const float4*)(rp + 4);
        float4 c = *(const float4*)(rp + 8);
        float wv[12] = { a.x, a.y, a.z, a.w, bb.x, bb.y, bb.z, bb.w,
                         c.x, c.y, c.z, c.w };

        // sliding box sums: pixel p covers window cols p+1..p+7
        float rs0 = ((wv[1] + wv[2]) + (wv[3] + wv[4])) + ((wv[5] + wv[6]) + wv[7]);
        float rs1 = rs0 - wv[1] + wv[8];
        float rs2 = rs1 - wv[2] + wv[9];
        float rs3 = rs2 - wv[3] + wv[10];
        bsum[0] += rs0; bsum[1] += rs1; bsum[2] += rs2; bsum[3] += rs3;

        // dif: column c touches pixels p with 0 <= c-1-p <= 6; consume v immediately
#pragma unroll
        for (int cc = 1; cc <= 10; cc++) {
            float v = wv[cc];
#pragma unroll
            for (int p = 0; p < 4; p++) {
                const int dj = cc - 1 - p;
                if (dj >= 0 && dj < 7)
                    dif[p] = fmaf(kw[r * 7 + dj], fmaxf(v - cen[p], 0.f), dif[p]);
            }
        }
    }

    const int gy = y0 + rt;
    const size_t gi = (size_t)b * (HW * HW) + (size_t)gy * HW + x0 + c0;

    float4 av, dv, rv;
    av.x = __expf(-bsum[0] * (1.0f / 49.0f));
    av.y = __expf(-bsum[1] * (1.0f / 49.0f));
    av.z = __expf(-bsum[2] * (1.0f / 49.0f));
    av.w = __expf(-bsum[3] * (1.0f / 49.0f));
    dv.x = dif[0]; dv.y = dif[1]; dv.z = dif[2]; dv.w = dif[3];

    float s0 = 0.1f * av.x + 0.9f * dv.x;   // s > 0 always (avg>0, dif>=0)
    float s1 = 0.1f * av.y + 0.9f * dv.y;
    float s2 = 0.1f * av.z + 0.9f * dv.z;
    float s3 = 0.1f * av.w + 0.9f * dv.w;

    rv.x = cen[0] / s0; rv.y = cen[1] / s1; rv.z = cen[2] / s2; rv.w = cen[3] / s3;

    *(float4*)(out_avg + gi)   = av;
    *(float4*)(out_dif + gi)   = dv;
    *(float4*)(out_ratio + gi) = rv;

    float ss = (s0 * s0 + s1 * s1) + (s2 * s2 + s3 * s3);
#pragma unroll
    for (int off = 32; off > 0; off >>= 1)
        ss += __shfl_down(ss, off, 64);
    if ((tid & 63) == 0) wsum[tid >> 6] = ss;
    __syncthreads();
    if (tid == 0)
        atomicAdd(ss_accum, (wsum[0] + wsum[1]) + (wsum[2] + wsum[3]));
}

// Phase 2: in-place over the mask slot: mask = (ratio > 1/sqrt(ss)).
__global__ __launch_bounds__(256) void li_phase2(
    const float* __restrict__ ss, float* __restrict__ io)
{
    const int i = (blockIdx.x * 256 + threadIdx.x) * 4;
    const float inv = 1.0f / sqrtf(*ss);
    float4 r = *(const float4*)(io + i);
    float4 m;
    m.x = (r.x > inv) ? 1.f : 0.f;
    m.y = (r.y > inv) ? 1.f : 0.f;
    m.z = (r.z > inv) ? 1.f : 0.f;
    m.w = (r.w > inv) ? 1.f : 0.f;
    *(float4*)(io + i) = m;
}

extern "C" void kernel_launch(void* const* d_in, const int* in_sizes, int n_in,
                              void* d_out, int out_size, void* d_ws, size_t ws_size,
                              hipStream_t stream) {
    const float* x  = (const float*)d_in[0];
    const float* kw = (const float*)d_in[1];
    float* out   = (float*)d_out;
    float* ratio = out;                       // becomes mask after phase 2
    float* avg   = out + N_PIX;
    float* dif   = out + 2 * (size_t)N_PIX;
    float* ss    = (float*)d_ws;

    hipMemsetAsync(d_ws, 0, sizeof(float), stream);

    dim3 g(HW / TLX, HW / TLY, NB);   // 4 x 64 x 16 = 4096 blocks
    li_phase1<<<g, 256, 0, stream>>>(x, kw, ratio, avg, dif, ss);
    li_phase2<<<N_PIX / 1024, 256, 0, stream>>>(ss, ratio);
}

// Round 4
// 100.841 us; speedup vs baseline: 1.4380x; 1.3596x over previous
//
#include <hip/hip_runtime.h>
#include <math.h>

#define HW 512
#define NB 16
#define TX 64           // tile width in pixels
#define TY 32           // tile height in pixels
#define LDSW 72         // TX + 8 (4-col halo each side, float4-aligned)
#define LDSH 38         // TY + 6
#define N_PIX (NB * HW * HW)   // 4194304
#define NBLK (8 * 16 * NB)     // 2048 phase-1 blocks

// Phase 1: 64x32 tile per block; thread = 1 column x 8 rows.
// Scalar b32 LDS reads (stride-1 lanes -> 2-way conflicts only, free).
// Writes avg, dif, ratio=x/s; per-block partial sum of s^2 to ws[flatid].
__global__ __launch_bounds__(256, 4) void li_phase1(
    const float* __restrict__ x, const float* __restrict__ kw,
    float* __restrict__ out_ratio, float* __restrict__ out_avg,
    float* __restrict__ out_dif, float* __restrict__ partials)
{
    __shared__ float tile[LDSH * LDSW];   // 10944 B
    __shared__ float wsum[4];

    const int tid = threadIdx.x;
    const int bx = blockIdx.x, by = blockIdx.y, b = blockIdx.z;
    const int x0 = bx * TX, y0 = by * TY;
    const float* xb = x + (size_t)b * (HW * HW);

    // Preload all 49 weights with uniform indices -> scalar loads, hoisted.
    float w[49];
#pragma unroll
    for (int i = 0; i < 49; i++) w[i] = kw[i];

    // Stage 38 x 72 tile, float4 granularity (quads fully in/out of bounds).
    for (int idx = tid; idx < LDSH * (LDSW / 4); idx += 256) {
        int r = idx / (LDSW / 4);
        int c4 = idx - r * (LDSW / 4);
        int gy = y0 - 3 + r;
        int gx = x0 - 4 + c4 * 4;
        float4 v = make_float4(0.f, 0.f, 0.f, 0.f);
        if ((unsigned)gy < HW && (unsigned)gx < HW)
            v = *(const float4*)(xb + gy * HW + gx);
        *(float4*)&tile[r * LDSW + c4 * 4] = v;
    }
    __syncthreads();

    const int tx  = tid & 63;        // column within tile
    const int ty0 = (tid >> 6) * 8;  // first of 8 output rows

    // Centers: output row p lives at LDS row ty0+p+3, LDS col tx+4.
    float cen[8];
#pragma unroll
    for (int p = 0; p < 8; p++)
        cen[p] = tile[(ty0 + p + 3) * LDSW + tx + 4];

    float dif[8]  = {0, 0, 0, 0, 0, 0, 0, 0};
    float vsum[14] = {0};

#pragma unroll
    for (int dj = 0; dj < 7; dj++) {
        float c[14];
#pragma unroll
        for (int r = 0; r < 14; r++)
            c[r] = tile[(ty0 + r) * LDSW + tx + 1 + dj];
#pragma unroll
        for (int r = 0; r < 14; r++)
            vsum[r] += c[r];
        // tap (row r, col dj) feeds output p where di = r-p in [0,7)
#pragma unroll
        for (int r = 0; r < 14; r++) {
#pragma unroll
            for (int p = 0; p < 8; p++) {
                const int di = r - p;
                if (di >= 0 && di < 7)
                    dif[p] = fmaf(w[di * 7 + dj], fmaxf(c[r] - cen[p], 0.f), dif[p]);
            }
        }
    }

    // Vertical sliding 7-sum of horizontal row sums -> box sums.
    float bsum[8];
    float s = ((vsum[0] + vsum[1]) + (vsum[2] + vsum[3])) +
              ((vsum[4] + vsum[5]) + vsum[6]);
    bsum[0] = s;
#pragma unroll
    for (int p = 1; p < 8; p++) {
        s += vsum[p + 6] - vsum[p - 1];
        bsum[p] = s;
    }

    const size_t base = (size_t)b * (HW * HW) + (size_t)(y0 + ty0) * HW + x0 + tx;
    float ss = 0.f;
#pragma unroll
    for (int p = 0; p < 8; p++) {
        float avg = __expf(-bsum[p] * (1.0f / 49.0f));
        float d = dif[p];
        float sp = 0.1f * avg + 0.9f * d;        // > 0 always
        size_t gi = base + (size_t)p * HW;
        out_avg[gi] = avg;
        out_dif[gi] = d;
        out_ratio[gi] = cen[p] / sp;
        ss = fmaf(sp, sp, ss);
    }

#pragma unroll
    for (int off = 32; off > 0; off >>= 1)
        ss += __shfl_down(ss, off, 64);
    if ((tid & 63) == 0) wsum[tid >> 6] = ss;
    __syncthreads();
    if (tid == 0) {
        int flat = bx + 8 * (by + 16 * b);
        partials[flat] = (wsum[0] + wsum[1]) + (wsum[2] + wsum[3]);
    }
}

// Reduce 2048 partials -> inv = 1/sqrt(sum), stored at ws[NBLK].
__global__ __launch_bounds__(256) void li_reduce(float* __restrict__ ws)
{
    __shared__ float wsum[4];
    const int tid = threadIdx.x;
    float s = 0.f;
#pragma unroll
    for (int i = 0; i < NBLK / 256; i++)
        s += ws[tid + i * 256];
#pragma unroll
    for (int off = 32; off > 0; off >>= 1)
        s += __shfl_down(s, off, 64);
    if ((tid & 63) == 0) wsum[tid >> 6] = s;
    __syncthreads();
    if (tid == 0)
        ws[NBLK] = 1.0f / sqrtf((wsum[0] + wsum[1]) + (wsum[2] + wsum[3]));
}

// Phase 2: in-place mask = (ratio > inv).
__global__ __launch_bounds__(256) void li_phase2(
    const float* __restrict__ ws, float* __restrict__ io)
{
    const int i = (blockIdx.x * 256 + threadIdx.x) * 4;
    const float inv = ws[NBLK];
    float4 r = *(const float4*)(io + i);
    float4 m;
    m.x = (r.x > inv) ? 1.f : 0.f;
    m.y = (r.y > inv) ? 1.f : 0.f;
    m.z = (r.z > inv) ? 1.f : 0.f;
    m.w = (r.w > inv) ? 1.f : 0.f;
    *(float4*)(io + i) = m;
}

extern "C" void kernel_launch(void* const* d_in, const int* in_sizes, int n_in,
                              void* d_out, int out_size, void* d_ws, size_t ws_size,
                              hipStream_t stream) {
    const float* x  = (const float*)d_in[0];
    const float* kw = (const float*)d_in[1];
    float* out   = (float*)d_out;
    float* ratio = out;                       // becomes mask after phase 2
    float* avg   = out + N_PIX;
    float* dif   = out + 2 * (size_t)N_PIX;
    float* ws    = (float*)d_ws;              // [0,NBLK): partials, [NBLK]: inv

    dim3 g(HW / TX, HW / TY, NB);   // 8 x 16 x 16 = 2048 blocks
    li_phase1<<<g, 256, 0, stream>>>(x, kw, ratio, avg, dif, ws);
    li_reduce<<<1, 256, 0, stream>>>(ws);
    li_phase2<<<N_PIX / 1024, 256, 0, stream>>>(ws, ratio);
}

// Round 5
// 97.239 us; speedup vs baseline: 1.4912x; 1.0370x over previous
//
#include <hip/hip_runtime.h>
#include <math.h>

#define HW 512
#define NB 16
#define TX 64           // tile width in pixels
#define TY 32           // tile height in pixels
#define LDSW 72         // TX + 8 (4-col halo each side, float4-aligned)
#define LDSH 38         // TY + 6
#define N_PIX (NB * HW * HW)   // 4194304
#define NBLK (8 * 16 * NB)     // 2048 phase-1 blocks

// Force a float into an SGPR.
__device__ __forceinline__ float sgpr_f(float v) {
    return __uint_as_float(__builtin_amdgcn_readfirstlane(__float_as_uint(v)));
}

// Phase 1: 64x32 tile per block; thread = 1 column x 8 rows.
// Row-streaming sweep: tiny live set (~35 VGPRs) -> 8 waves/SIMD.
__global__ __launch_bounds__(256, 8) void li_phase1(
    const float* __restrict__ x, const float* __restrict__ kw,
    float* __restrict__ out_ratio, float* __restrict__ out_avg,
    float* __restrict__ out_dif, float* __restrict__ partials)
{
    __shared__ float tile[LDSH * LDSW];   // 10944 B
    __shared__ float wsum[4];

    const int tid = threadIdx.x;
    const int bx = blockIdx.x, by = blockIdx.y, b = blockIdx.z;
    const int x0 = bx * TX, y0 = by * TY;
    const float* xb = x + (size_t)b * (HW * HW);

    // All 49 weights pinned to SGPRs (uniform), zero per-tap load cost.
    float w[49];
#pragma unroll
    for (int i = 0; i < 49; i++) w[i] = sgpr_f(kw[i]);

    // Stage 38 x 72 tile, float4 granularity (quads fully in/out of bounds).
    for (int idx = tid; idx < LDSH * (LDSW / 4); idx += 256) {
        int r = idx / (LDSW / 4);
        int c4 = idx - r * (LDSW / 4);
        int gy = y0 - 3 + r;
        int gx = x0 - 4 + c4 * 4;
        float4 v = make_float4(0.f, 0.f, 0.f, 0.f);
        if ((unsigned)gy < HW && (unsigned)gx < HW)
            v = *(const float4*)(xb + gy * HW + gx);
        *(float4*)&tile[r * LDSW + c4 * 4] = v;
    }
    __syncthreads();

    const int tx  = tid & 63;        // column within tile
    const int ty0 = (tid >> 6) * 8;  // first of 8 output rows

    // Centers: output row p at LDS (ty0+p+3, tx+4). All 8 pixels share column tx.
    float cen[8];
#pragma unroll
    for (int p = 0; p < 8; p++)
        cen[p] = tile[(ty0 + p + 3) * LDSW + tx + 4];

    float dif[8]  = {0, 0, 0, 0, 0, 0, 0, 0};
    float bsum[8] = {0, 0, 0, 0, 0, 0, 0, 0};

    // Stream rows: window row r feeds pixels p with di = r-p in [0,7).
#pragma unroll
    for (int r = 0; r < 14; r++) {
        float v[7];
#pragma unroll
        for (int dj = 0; dj < 7; dj++)
            v[dj] = tile[(ty0 + r) * LDSW + tx + 1 + dj];

        float rs = ((v[0] + v[1]) + (v[2] + v[3])) + ((v[4] + v[5]) + v[6]);
#pragma unroll
        for (int p = 0; p < 8; p++) {
            const int di = r - p;
            if (di >= 0 && di < 7) {
                bsum[p] += rs;
#pragma unroll
                for (int dj = 0; dj < 7; dj++)
                    dif[p] = fmaf(w[di * 7 + dj], fmaxf(v[dj] - cen[p], 0.f), dif[p]);
            }
        }
    }

    const size_t base = (size_t)b * (HW * HW) + (size_t)(y0 + ty0) * HW + x0 + tx;
    float ss = 0.f;
#pragma unroll
    for (int p = 0; p < 8; p++) {
        float avg = __expf(-bsum[p] * (1.0f / 49.0f));
        float d = dif[p];
        float sp = 0.1f * avg + 0.9f * d;        // > 0 always
        size_t gi = base + (size_t)p * HW;
        __builtin_nontemporal_store(avg, out_avg + gi);   // never re-read on device
        __builtin_nontemporal_store(d,   out_dif + gi);
        out_ratio[gi] = cen[p] * __builtin_amdgcn_rcpf(sp);
        ss = fmaf(sp, sp, ss);
    }

#pragma unroll
    for (int off = 32; off > 0; off >>= 1)
        ss += __shfl_down(ss, off, 64);
    if ((tid & 63) == 0) wsum[tid >> 6] = ss;
    __syncthreads();
    if (tid == 0) {
        int flat = bx + 8 * (by + 16 * b);
        partials[flat] = (wsum[0] + wsum[1]) + (wsum[2] + wsum[3]);
    }
}

// Reduce 2048 partials -> inv = 1/sqrt(sum), stored at ws[NBLK].
__global__ __launch_bounds__(256) void li_reduce(float* __restrict__ ws)
{
    __shared__ float wsum[4];
    const int tid = threadIdx.x;
    float s = 0.f;
#pragma unroll
    for (int i = 0; i < NBLK / 256; i++)
        s += ws[tid + i * 256];
#pragma unroll
    for (int off = 32; off > 0; off >>= 1)
        s += __shfl_down(s, off, 64);
    if ((tid & 63) == 0) wsum[tid >> 6] = s;
    __syncthreads();
    if (tid == 0)
        ws[NBLK] = 1.0f / sqrtf((wsum[0] + wsum[1]) + (wsum[2] + wsum[3]));
}

// Phase 2: in-place mask = (ratio > inv).
__global__ __launch_bounds__(256) void li_phase2(
    const float* __restrict__ ws, float* __restrict__ io)
{
    const int i = (blockIdx.x * 256 + threadIdx.x) * 4;
    const float inv = ws[NBLK];
    float4 r = *(const float4*)(io + i);
    float4 m;
    m.x = (r.x > inv) ? 1.f : 0.f;
    m.y = (r.y > inv) ? 1.f : 0.f;
    m.z = (r.z > inv) ? 1.f : 0.f;
    m.w = (r.w > inv) ? 1.f : 0.f;
    *(float4*)(io + i) = m;
}

extern "C" void kernel_launch(void* const* d_in, const int* in_sizes, int n_in,
                              void* d_out, int out_size, void* d_ws, size_t ws_size,
                              hipStream_t stream) {
    const float* x  = (const float*)d_in[0];
    const float* kw = (const float*)d_in[1];
    float* out   = (float*)d_out;
    float* ratio = out;                       // becomes mask after phase 2
    float* avg   = out + N_PIX;
    float* dif   = out + 2 * (size_t)N_PIX;
    float* ws    = (float*)d_ws;              // [0,NBLK): partials, [NBLK]: inv

    dim3 g(HW / TX, HW / TY, NB);   // 8 x 16 x 16 = 2048 blocks
    li_phase1<<<g, 256, 0, stream>>>(x, kw, ratio, avg, dif, ws);
    li_reduce<<<1, 256, 0, stream>>>(ws);
    li_phase2<<<N_PIX / 1024, 256, 0, stream>>>(ws, ratio);
}